// Round 2
// baseline (131.085 us; speedup 1.0000x reference)
//
#include <hip/hip_runtime.h>
#include <math.h>

#define NB   8
#define TD   64
#define TE   1024
#define DDIM 256
#define UDIM 128

__device__ __forceinline__ float rcp_fast(float x) {
    return __builtin_amdgcn_rcpf(x);   // v_rcp_f32 — fine downstream of softmax
}

// ---------------------------------------------------------------------------
// Kernel 1: E = exp(2*(X @ W + b)) for encoder (8192 rows) and decoder (512).
// 16 rows/block, 256 threads. Transposed LDS staging; thread owns (u-pair, 4
// rows). tanh(a+c) = 1 - 2/(e^{2a} e^{2c} + 1) -> store e^{2w} once per row.
// ---------------------------------------------------------------------------
__global__ __launch_bounds__(256) void k_compute_E(
    const float* __restrict__ enc, const float* __restrict__ dec,
    const float* __restrict__ W1, const float* __restrict__ b1,
    const float* __restrict__ W2, const float* __restrict__ b2,
    float* __restrict__ E_enc, float* __restrict__ E_dec)
{
    __shared__ alignas(16) float ldsT[DDIM][20];  // [d][r], r<16, pad->20

    const int blk = blockIdx.x;
    const float *W, *bias, *in;
    float *out;
    if (blk < 512) {                    // encoder rows
        in   = enc + (size_t)blk * 16 * DDIM;
        W    = W1;  bias = b1;
        out  = E_enc + (size_t)blk * 16 * UDIM;
    } else {                            // decoder rows
        const int bd = blk - 512;
        in   = dec + (size_t)bd * 16 * DDIM;
        W    = W2;  bias = b2;
        out  = E_dec + (size_t)bd * 16 * UDIM;
    }

    const int tid = threadIdx.x;
    for (int i = tid; i < 16 * DDIM; i += 256) {
        const int r = i >> 8;
        const int d = i & 255;
        ldsT[d][r] = in[i];
    }
    __syncthreads();

    const int u0 = (tid & 63) * 2;      // u-pair
    const int r0 = (tid >> 6) * 4;      // 4 rows, wave-uniform -> LDS broadcast

    float acc[4][2];
    #pragma unroll
    for (int r = 0; r < 4; ++r) { acc[r][0] = 0.f; acc[r][1] = 0.f; }

    #pragma unroll 4
    for (int d = 0; d < DDIM; ++d) {
        const float2 w2 = *(const float2*)(W + d * UDIM + u0);   // coalesced
        const float4 a4 = *(const float4*)(&ldsT[d][r0]);        // broadcast
        acc[0][0] = fmaf(a4.x, w2.x, acc[0][0]); acc[0][1] = fmaf(a4.x, w2.y, acc[0][1]);
        acc[1][0] = fmaf(a4.y, w2.x, acc[1][0]); acc[1][1] = fmaf(a4.y, w2.y, acc[1][1]);
        acc[2][0] = fmaf(a4.z, w2.x, acc[2][0]); acc[2][1] = fmaf(a4.z, w2.y, acc[2][1]);
        acc[3][0] = fmaf(a4.w, w2.x, acc[3][0]); acc[3][1] = fmaf(a4.w, w2.y, acc[3][1]);
    }

    const float k2l2e = 2.0f * 1.4426950408889634f;  // 2*log2(e)
    const float bb0 = bias[u0], bb1 = bias[u0 + 1];
    #pragma unroll
    for (int r = 0; r < 4; ++r) {
        const float e0 = exp2f((acc[r][0] + bb0) * k2l2e);
        const float e1 = exp2f((acc[r][1] + bb1) * k2l2e);
        *(float2*)(out + (size_t)(r0 + r) * UDIM + u0) = make_float2(e0, e1);
    }
}

// ---------------------------------------------------------------------------
// Kernel 2 (fused): score + softmax + context for one (b, t-pair).
// 256 blocks x 1024 threads (1 block/CU).
// Phase A: thread s computes score'(t,s) = -2 * sum_u V_u * rcp(1 + E_s E_t)
//          (tanh identity; constant shift sum(V)+bV cancels in softmax).
//          E_dec rows + V read via wave-uniform pointers -> s_load broadcasts.
// Softmax: shfl + LDS block reduction (max, then sum), attn -> LDS.
// Phase B: thread (d-pair, s-chunk of 128): ctx partial; LDS cross-chunk
//          reduction; coalesced store to d_out. No attn/partials in ws.
// ---------------------------------------------------------------------------
__global__ __launch_bounds__(1024) void k_fused(
    const float* __restrict__ E_enc, const float* __restrict__ E_dec,
    const float* __restrict__ V, const float* __restrict__ enc,
    float* __restrict__ out)
{
    __shared__ alignas(16) float pa[TE];           // attn row t0
    __shared__ alignas(16) float pb[TE];           // attn row t0+1
    __shared__ alignas(16) float red[8][2][DDIM];  // 16 KB ctx partials
    __shared__ float redm[16][2];
    __shared__ float reds[16][2];

    const int blk = blockIdx.x;        // 0..255
    const int b   = blk >> 5;
    const int t0  = (blk & 31) * 2;
    const int tid = threadIdx.x;

    // wave-uniform row pointers (compiler scalarizes these loads)
    const float* er0 = E_dec + (size_t)(b * TD + t0) * UDIM;
    const float* er1 = er0 + UDIM;

    // ---- Phase A: scores ----
    const int s = tid;
    const float* erow = E_enc + (size_t)(b * TE + s) * UDIM;

    float acc0 = 0.f, acc1 = 0.f;
    #pragma unroll 8
    for (int u = 0; u < UDIM; u += 4) {
        const float4 e  = *(const float4*)(erow + u);
        const float4 a0 = *(const float4*)(er0 + u);   // uniform -> s_load
        const float4 a1 = *(const float4*)(er1 + u);   // uniform -> s_load
        const float4 vv = *(const float4*)(V + u);     // uniform -> s_load
        acc0 = fmaf(vv.x, rcp_fast(fmaf(e.x, a0.x, 1.f)), acc0);
        acc1 = fmaf(vv.x, rcp_fast(fmaf(e.x, a1.x, 1.f)), acc1);
        acc0 = fmaf(vv.y, rcp_fast(fmaf(e.y, a0.y, 1.f)), acc0);
        acc1 = fmaf(vv.y, rcp_fast(fmaf(e.y, a1.y, 1.f)), acc1);
        acc0 = fmaf(vv.z, rcp_fast(fmaf(e.z, a0.z, 1.f)), acc0);
        acc1 = fmaf(vv.z, rcp_fast(fmaf(e.z, a1.z, 1.f)), acc1);
        acc0 = fmaf(vv.w, rcp_fast(fmaf(e.w, a0.w, 1.f)), acc0);
        acc1 = fmaf(vv.w, rcp_fast(fmaf(e.w, a1.w, 1.f)), acc1);
    }
    acc0 *= -2.0f;   // fold the (-2 V_u) weight
    acc1 *= -2.0f;

    // ---- block max over 1024 s ----
    float m0 = acc0, m1 = acc1;
    #pragma unroll
    for (int off = 32; off; off >>= 1) {
        m0 = fmaxf(m0, __shfl_xor(m0, off));
        m1 = fmaxf(m1, __shfl_xor(m1, off));
    }
    const int wv = tid >> 6;
    if ((tid & 63) == 0) { redm[wv][0] = m0; redm[wv][1] = m1; }
    __syncthreads();
    float gm0 = -3.4e38f, gm1 = -3.4e38f;
    #pragma unroll
    for (int i = 0; i < 16; ++i) {
        gm0 = fmaxf(gm0, redm[i][0]);
        gm1 = fmaxf(gm1, redm[i][1]);
    }

    const float p0 = __expf(acc0 - gm0);
    const float p1 = __expf(acc1 - gm1);

    // ---- block sum ----
    float s0 = p0, s1 = p1;
    #pragma unroll
    for (int off = 32; off; off >>= 1) {
        s0 += __shfl_xor(s0, off);
        s1 += __shfl_xor(s1, off);
    }
    if ((tid & 63) == 0) { reds[wv][0] = s0; reds[wv][1] = s1; }
    __syncthreads();
    float gs0 = 0.f, gs1 = 0.f;
    #pragma unroll
    for (int i = 0; i < 16; ++i) { gs0 += reds[i][0]; gs1 += reds[i][1]; }

    pa[s] = p0 * rcp_fast(gs0);
    pb[s] = p1 * rcp_fast(gs1);
    __syncthreads();

    // ---- Phase B: context = attn @ enc[b] ----
    const int dp = tid & 127;          // d-pair -> d0 = dp*2
    const int d0 = dp * 2;
    const int sq = tid >> 7;           // s-chunk (8 chunks of 128), wave-uniform
    const float* ebase = enc + ((size_t)(b * TE + sq * 128)) * DDIM + d0;

    float c00 = 0.f, c01 = 0.f, c10 = 0.f, c11 = 0.f;
    #pragma unroll 4
    for (int ss = 0; ss < 128; ++ss) {
        const float a0 = pa[sq * 128 + ss];            // LDS broadcast
        const float a1 = pb[sq * 128 + ss];            // LDS broadcast
        const float2 e = *(const float2*)(ebase + (size_t)ss * DDIM);
        c00 = fmaf(a0, e.x, c00);
        c01 = fmaf(a0, e.y, c01);
        c10 = fmaf(a1, e.x, c10);
        c11 = fmaf(a1, e.y, c11);
    }
    *(float2*)(&red[sq][0][d0]) = make_float2(c00, c01);
    *(float2*)(&red[sq][1][d0]) = make_float2(c10, c11);
    __syncthreads();

    if (tid < 512) {
        const int t = tid >> 8;        // 0/1
        const int d = tid & 255;
        float r = 0.f;
        #pragma unroll
        for (int q = 0; q < 8; ++q) r += red[q][t][d];
        out[(size_t)(b * TD + t0 + t) * DDIM + d] = r;
    }
}

extern "C" void kernel_launch(void* const* d_in, const int* in_sizes, int n_in,
                              void* d_out, int out_size, void* d_ws, size_t ws_size,
                              hipStream_t stream) {
    const float* dec = (const float*)d_in[0];   // [8,64,256]
    const float* enc = (const float*)d_in[1];   // [8,1024,256]
    const float* W1  = (const float*)d_in[2];   // [256,128]
    const float* b1  = (const float*)d_in[3];   // [128]
    const float* W2  = (const float*)d_in[4];   // [256,128]
    const float* b2  = (const float*)d_in[5];   // [128]
    const float* V   = (const float*)d_in[6];   // [128,1]
    // d_in[7] = bV: constant shift, cancels in softmax -> unused.

    float* ws    = (float*)d_ws;
    float* E_enc = ws;                                   // 8*1024*128 floats
    float* E_dec = E_enc + (size_t)NB * TE * UDIM;       // 8*64*128 floats
    // ws use: ~4.3 MB total

    k_compute_E<<<544, 256,  0, stream>>>(enc, dec, W1, b1, W2, b2, E_enc, E_dec);
    k_fused    <<<256, 1024, 0, stream>>>(E_enc, E_dec, V, enc, (float*)d_out);
}